// Round 1
// baseline (3745.055 us; speedup 1.0000x reference)
//
#include <hip/hip_runtime.h>
#include <hip/hip_bf16.h>

#define TPB 256
constexpr int B_ = 256, S_ = 512, D_ = 512, Q_ = 256, NM_ = 512;
constexpr int NB = 64, NT = 8;

// ---------------- stats: masks, counts, means ----------------
__global__ __launch_bounds__(TPB) void k_stats(const float* __restrict__ X,
                                               const int* __restrict__ labels,
                                               const int* __restrict__ slen,
                                               float* __restrict__ mu,
                                               float* __restrict__ w,
                                               float* __restrict__ cnt)
{
  int b = blockIdx.x, t = threadIdx.x;
  __shared__ int lab[S_];
  __shared__ float red[TPB];
  int L = slen[b];
  for (int s = t; s < S_; s += TPB) {
    int lb = labels[b*S_ + s];
    int eff = (s < L) ? lb : -1;
    lab[s] = eff;
    w[(b*2+0)*S_ + s] = (eff==0) ? 1.f : 0.f;
    w[(b*2+1)*S_ + s] = (eff==1) ? 1.f : 0.f;
  }
  __syncthreads();
  int cpi=0, cni=0;
  for (int s=t; s<S_; s+=TPB){ cpi += (lab[s]==1); cni += (lab[s]==0); }
  red[t] = (float)cpi; __syncthreads();
  for (int o=TPB/2;o>0;o>>=1){ if(t<o) red[t]+=red[t+o]; __syncthreads(); }
  float cp = red[0]; __syncthreads();
  red[t] = (float)cni; __syncthreads();
  for (int o=TPB/2;o>0;o>>=1){ if(t<o) red[t]+=red[t+o]; __syncthreads(); }
  float cn = red[0];
  if (t==0){ cnt[b*2+0]=cn; cnt[b*2+1]=cp; }
  float sp0=0,sp1=0,sn0=0,sn1=0;
  const float* Xb = X + (size_t)b*S_*D_;
  for (int s=0;s<S_;s++){
    int e = lab[s];
    if (e < 0) continue;
    float x0 = Xb[(size_t)s*D_ + t];
    float x1 = Xb[(size_t)s*D_ + t + 256];
    if (e==1){ sp0+=x0; sp1+=x1; } else { sn0+=x0; sn1+=x1; }
  }
  float st = (float)L;
  float* mb = mu + (size_t)b*3*D_;
  mb[0*D_ + t] = sn0/cn;       mb[0*D_ + t+256] = sn1/cn;
  mb[1*D_ + t] = sp0/cp;       mb[1*D_ + t+256] = sp1/cp;
  mb[2*D_ + t] = (sn0+sp0)/st; mb[2*D_ + t+256] = (sn1+sp1)/st;
}

// ---------------- Gram tiles -> A matrices (fused rank-1 + ridge) ----------------
__global__ __launch_bounds__(TPB) void k_gram(const float* __restrict__ X,
                                              const float* __restrict__ w,
                                              const float* __restrict__ mu,
                                              const float* __restrict__ cnt,
                                              const int* __restrict__ slen,
                                              float* __restrict__ A)
{
  int b = blockIdx.y;
  int z = blockIdx.x;                 // 0..35 -> upper-triangle tile (ti,tj)
  int ti = 0, rem = z;
  while (rem >= NT - ti){ rem -= NT - ti; ti++; }
  int tj = ti + rem;
  int i0 = ti*NB, j0 = tj*NB;
  int t = threadIdx.x, tr = t & 15, tc = t >> 4;
  __shared__ float Xi[32][68], Xj[32][68];
  __shared__ float wsh[2][32];
  float accp[4][4] = {}, accn[4][4] = {};
  const float* Xb = X + (size_t)b*S_*D_;
  for (int s0=0; s0<S_; s0+=32){
    #pragma unroll
    for (int p=0;p<2;p++){
      int idx = t + 256*p;            // 512 float4 slots
      int row = idx >> 4, c4 = idx & 15;
      const float4* srci = (const float4*)(Xb + (size_t)(s0+row)*D_ + i0);
      const float4* srcj = (const float4*)(Xb + (size_t)(s0+row)*D_ + j0);
      *((float4*)&Xi[row][c4*4]) = srci[c4];
      *((float4*)&Xj[row][c4*4]) = srcj[c4];
    }
    if (t < 64){
      int cl = t >> 5, ss = t & 31;
      wsh[cl][ss] = w[(b*2+cl)*S_ + s0 + ss];
    }
    __syncthreads();
    #pragma unroll 4
    for (int ss=0; ss<32; ss++){
      float wn = wsh[0][ss], wp = wsh[1][ss];
      float4 xiv = *((const float4*)&Xi[ss][tr*4]);
      float4 xjv = *((const float4*)&Xj[ss][tc*4]);
      float xi[4] = {xiv.x, xiv.y, xiv.z, xiv.w};
      float xj[4] = {xjv.x, xjv.y, xjv.z, xjv.w};
      #pragma unroll
      for (int u=0;u<4;u++){
        float tp = wp*xi[u], tn = wn*xi[u];
        #pragma unroll
        for (int v=0;v<4;v++){
          accp[u][v] = fmaf(tp, xj[v], accp[u][v]);
          accn[u][v] = fmaf(tn, xj[v], accn[u][v]);
        }
      }
    }
    __syncthreads();
  }
  float cn = cnt[b*2+0], cp = cnt[b*2+1];
  float st = (float)slen[b];
  float kn = 0.1f/(cn-1.f), kp = 0.1f/(cp-1.f), kt = 0.9f/(st-1.f);
  float rn = 0.1f*cn/(cn-1.f), rp = 0.1f*cp/(cp-1.f), rt = 0.9f*st/(st-1.f);
  const float* mb = mu + (size_t)b*3*D_;
  float mni[4], mpi[4], mti[4], mnj[4], mpj[4], mtj[4];
  #pragma unroll
  for (int u=0;u<4;u++){ int r = i0 + tr*4+u; mni[u]=mb[0*D_+r]; mpi[u]=mb[1*D_+r]; mti[u]=mb[2*D_+r]; }
  #pragma unroll
  for (int v=0;v<4;v++){ int c = j0 + tc*4+v; mnj[v]=mb[0*D_+c]; mpj[v]=mb[1*D_+c]; mtj[v]=mb[2*D_+c]; }
  float* A0 = A + (size_t)(b*2+0)*D_*D_;
  float* A1 = A + (size_t)(b*2+1)*D_*D_;
  #pragma unroll
  for (int u=0;u<4;u++){
    #pragma unroll
    for (int v=0;v<4;v++){
      int r = i0 + tr*4+u, c = j0 + tc*4+v;
      float gp = accp[u][v], gn = accn[u][v];
      float diag = (r==c) ? 0.1f : 0.f;
      float a0 = (kn+kt)*gn + kt*gp - rn*mni[u]*mnj[v] - rt*mti[u]*mtj[v] + diag;
      float a1 = (kp+kt)*gp + kt*gn - rp*mpi[u]*mpj[v] - rt*mti[u]*mtj[v] + diag;
      A0[(size_t)r*D_ + c] = a0; A0[(size_t)c*D_ + r] = a0;
      A1[(size_t)r*D_ + c] = a1; A1[(size_t)c*D_ + r] = a1;
    }
  }
}

// ---------------- diag block Cholesky + triangular inverse ----------------
__global__ __launch_bounds__(TPB) void k_chol_diag(float* __restrict__ A,
                                                   float* __restrict__ invD, int j)
{
  int m = blockIdx.x, t = threadIdx.x;
  __shared__ float Ld[64][65];
  __shared__ float Iv[64][65];
  float* Ab = A + (size_t)m*D_*D_ + (size_t)(j*NB)*D_ + j*NB;
  for (int l=t; l<4096; l+=TPB){ int r=l>>6, c=l&63; Ld[r][c] = Ab[(size_t)r*D_ + c]; Iv[r][c] = 0.f; }
  __syncthreads();
  for (int k=0;k<64;k++){
    if (t==0) Ld[k][k] = sqrtf(Ld[k][k]);
    __syncthreads();
    if (t>k && t<64) Ld[t][k] /= Ld[k][k];
    __syncthreads();
    for (int l=t; l<4096; l+=TPB){
      int r=l>>6, c=l&63;
      if (r>k && c>k) Ld[r][c] = fmaf(-Ld[r][k], Ld[c][k], Ld[r][c]);
    }
    __syncthreads();
  }
  if (t < 64){
    int c = t;
    Iv[c][c] = 1.f/Ld[c][c];
    for (int r=c+1;r<64;r++){
      float s = 0.f;
      for (int k2=c;k2<r;k2++) s += Ld[r][k2]*Iv[k2][c];
      Iv[r][c] = -s/Ld[r][r];
    }
  }
  __syncthreads();
  float* Ib = invD + ((size_t)m*8 + j)*4096;
  for (int l=t; l<4096; l+=TPB){ int r=l>>6, c=l&63; Ib[l] = Iv[r][c]; }
}

// stage transposed: dst[col][row] = src[row][col], 64x64 tile
__device__ __forceinline__ void stage_T(const float* __restrict__ src, size_t ld,
                                        float (*dst)[68], int t)
{
  int r = t >> 2, seg = (t & 3) * 16;
  const float4* s4 = (const float4*)(src + (size_t)r*ld + seg);
  #pragma unroll
  for (int i=0;i<4;i++){
    float4 v = s4[i];
    dst[seg + i*4 + 0][r] = v.x;
    dst[seg + i*4 + 1][r] = v.y;
    dst[seg + i*4 + 2][r] = v.z;
    dst[seg + i*4 + 3][r] = v.w;
  }
}

// ---------------- panel: L_ij = A_ij * invD^T ----------------
__global__ __launch_bounds__(TPB) void k_panel(float* __restrict__ A,
                                               const float* __restrict__ invD, int j)
{
  int m = blockIdx.y, ib = j + 1 + blockIdx.x;
  int t = threadIdx.x, tr = t & 15, tc = t >> 4;
  __shared__ float Ta[64][68], Tb[64][68];
  float* Ablk = A + (size_t)m*D_*D_ + (size_t)(ib*NB)*D_ + j*NB;
  const float* Ib = invD + ((size_t)m*8 + j)*4096;
  stage_T(Ablk, D_, Ta, t);   // Ta[t][r] = A_ij[r][t]
  stage_T(Ib, 64, Tb, t);     // Tb[t][c] = invD[c][t]
  __syncthreads();
  float acc[4][4] = {};
  for (int kk=0; kk<64; kk++){
    float4 av = *((const float4*)&Ta[kk][tr*4]);
    float4 bv = *((const float4*)&Tb[kk][tc*4]);
    float a[4]={av.x,av.y,av.z,av.w}, bb[4]={bv.x,bv.y,bv.z,bv.w};
    #pragma unroll
    for (int u=0;u<4;u++)
      #pragma unroll
      for (int v=0;v<4;v++) acc[u][v] = fmaf(a[u], bb[v], acc[u][v]);
  }
  #pragma unroll
  for (int u=0;u<4;u++){
    float4 o = make_float4(acc[u][0],acc[u][1],acc[u][2],acc[u][3]);
    *((float4*)(Ablk + (size_t)(tr*4+u)*D_ + tc*4)) = o;
  }
}

// ---------------- trailing: A_ik -= L_ij * L_kj^T ----------------
__global__ __launch_bounds__(TPB) void k_trail(float* __restrict__ A, int j)
{
  int m = blockIdx.y, p = blockIdx.x;
  int T = NT - 1 - j;
  int kk = 0, rem = p;
  while (rem >= T - kk){ rem -= T - kk; kk++; }
  int kb = j + 1 + kk, ib = kb + rem;
  int t = threadIdx.x, tr = t & 15, tc = t >> 4;
  __shared__ float Ta[64][68], Tb[64][68];
  const float* Li = A + (size_t)m*D_*D_ + (size_t)(ib*NB)*D_ + j*NB;
  const float* Lk = A + (size_t)m*D_*D_ + (size_t)(kb*NB)*D_ + j*NB;
  stage_T(Li, D_, Ta, t);
  stage_T(Lk, D_, Tb, t);
  __syncthreads();
  float acc[4][4] = {};
  for (int t64=0;t64<64;t64++){
    float4 av = *((const float4*)&Ta[t64][tr*4]);
    float4 bv = *((const float4*)&Tb[t64][tc*4]);
    float a[4]={av.x,av.y,av.z,av.w}, bb[4]={bv.x,bv.y,bv.z,bv.w};
    #pragma unroll
    for (int u=0;u<4;u++)
      #pragma unroll
      for (int v=0;v<4;v++) acc[u][v] = fmaf(a[u], bb[v], acc[u][v]);
  }
  float* Cb = A + (size_t)m*D_*D_ + (size_t)(ib*NB)*D_ + kb*NB;
  #pragma unroll
  for (int u=0;u<4;u++){
    float4* pC = (float4*)(Cb + (size_t)(tr*4+u)*D_ + tc*4);
    float4 o = *pC;
    o.x -= acc[u][0]; o.y -= acc[u][1]; o.z -= acc[u][2]; o.w -= acc[u][3];
    *pC = o;
  }
}

// ---------------- R = mean - query^T  (into Z, [m, D, Q]) ----------------
__global__ __launch_bounds__(TPB) void k_rform(const float* __restrict__ Qs,
                                               const float* __restrict__ mu,
                                               float* __restrict__ Z)
{
  int m = blockIdx.y, b = m >> 1, cls = m & 1;
  int d0 = (blockIdx.x >> 2) * 64, q0 = (blockIdx.x & 3) * 64;
  int t = threadIdx.x;
  __shared__ float Tl[64][68];
  stage_T(Qs + ((size_t)b*Q_ + q0)*D_ + d0, D_, Tl, t);  // Tl[d][q]
  __syncthreads();
  const float* muc = mu + ((size_t)b*3 + cls)*D_;
  int dd = t >> 2, seg = (t & 3) * 16;
  float mv = muc[d0 + dd];
  float* Zr = Z + ((size_t)m*D_ + d0 + dd)*Q_ + q0 + seg;
  #pragma unroll
  for (int i=0;i<16;i+=4){
    float4 o = make_float4(mv - Tl[dd][seg+i], mv - Tl[dd][seg+i+1],
                           mv - Tl[dd][seg+i+2], mv - Tl[dd][seg+i+3]);
    *((float4*)(Zr + i)) = o;
  }
}

// ---------------- blocked forward solve step j (in place on Z) ----------------
__global__ __launch_bounds__(TPB) void k_solve(float* __restrict__ Z,
                                               const float* __restrict__ A,
                                               const float* __restrict__ invD, int j)
{
  int m = blockIdx.y, q0 = blockIdx.x * 64;
  int t = threadIdx.x, tr = t & 15, tc = t >> 4;
  __shared__ float Ta[64][68], Tb[64][68];
  float acc[4][4];
  float* Zm = Z + (size_t)m*D_*Q_;
  #pragma unroll
  for (int u=0;u<4;u++){
    float4 v = *((const float4*)(Zm + (size_t)(j*NB + tr*4+u)*Q_ + q0 + tc*4));
    acc[u][0]=v.x; acc[u][1]=v.y; acc[u][2]=v.z; acc[u][3]=v.w;
  }
  const float* Am = A + (size_t)m*D_*D_;
  for (int k=0;k<j;k++){
    stage_T(Am + (size_t)(j*NB)*D_ + k*NB, D_, Ta, t);   // Ta[t][r] = L_jk[r][t]
    {
      int r = t >> 2, seg = (t & 3)*16;
      const float4* s4 = (const float4*)(Zm + (size_t)(k*NB + r)*Q_ + q0 + seg);
      #pragma unroll
      for (int i=0;i<4;i++) *((float4*)&Tb[r][seg + i*4]) = s4[i];
    }
    __syncthreads();
    for (int t64=0;t64<64;t64++){
      float4 av = *((const float4*)&Ta[t64][tr*4]);
      float4 bv = *((const float4*)&Tb[t64][tc*4]);
      float a[4]={av.x,av.y,av.z,av.w}, bb[4]={bv.x,bv.y,bv.z,bv.w};
      #pragma unroll
      for (int u=0;u<4;u++)
        #pragma unroll
        for (int v=0;v<4;v++) acc[u][v] = fmaf(-a[u], bb[v], acc[u][v]);
    }
    __syncthreads();
  }
  // S -> Tb; invD -> Ta; Z_j = invD * S
  #pragma unroll
  for (int u=0;u<4;u++)
    #pragma unroll
    for (int v=0;v<4;v++) Tb[tr*4+u][tc*4+v] = acc[u][v];
  stage_T(invD + ((size_t)m*8 + j)*4096, 64, Ta, t);
  __syncthreads();
  float out[4][4] = {};
  for (int t64=0;t64<64;t64++){
    float4 av = *((const float4*)&Ta[t64][tr*4]);
    float4 bv = *((const float4*)&Tb[t64][tc*4]);
    float a[4]={av.x,av.y,av.z,av.w}, bb[4]={bv.x,bv.y,bv.z,bv.w};
    #pragma unroll
    for (int u=0;u<4;u++)
      #pragma unroll
      for (int v=0;v<4;v++) out[u][v] = fmaf(a[u], bb[v], out[u][v]);
  }
  #pragma unroll
  for (int u=0;u<4;u++){
    float4 o = make_float4(out[u][0], out[u][1], out[u][2], out[u][3]);
    *((float4*)(Zm + (size_t)(j*NB + tr*4+u)*Q_ + q0 + tc*4)) = o;
  }
}

// ---------------- maha + logits ----------------
__global__ __launch_bounds__(TPB) void k_final(const float* __restrict__ Z,
                                               const int* __restrict__ qlen,
                                               const float* __restrict__ lps,
                                               float* __restrict__ out)
{
  int b = blockIdx.x, q = threadIdx.x;
  float s2 = expf(2.f * lps[0]);
  const float* Zn = Z + (size_t)(b*2+0)*D_*Q_ + q;
  const float* Zp = Z + (size_t)(b*2+1)*D_*Q_ + q;
  float an=0.f, ap=0.f;
  #pragma unroll 8
  for (int d=0; d<D_; d++){
    float zn = Zn[(size_t)d*Q_]; an = fmaf(zn, zn, an);
    float zp = Zp[(size_t)d*Q_]; ap = fmaf(zp, zp, ap);
  }
  float valid = (q < qlen[b]) ? 1.f : 0.f;
  out[((size_t)b*Q_ + q)*2 + 0] = -s2*an*valid;
  out[((size_t)b*Q_ + q)*2 + 1] = -s2*ap*valid;
}

extern "C" void kernel_launch(void* const* d_in, const int* in_sizes, int n_in,
                              void* d_out, int out_size, void* d_ws, size_t ws_size,
                              hipStream_t stream) {
  (void)in_sizes; (void)n_in; (void)out_size;
  const float* X   = (const float*)d_in[0];
  const int*   lab = (const int*)d_in[1];
  const float* Qs  = (const float*)d_in[2];
  const int*   sl  = (const int*)d_in[3];
  const int*   ql  = (const int*)d_in[4];
  const float* lps = (const float*)d_in[5];
  float* out = (float*)d_out;

  float* A    = (float*)d_ws;                       // [512, 512, 512]
  float* Z    = A + (size_t)NM_*D_*D_;              // [512, 512, 256]
  float* invD = Z + (size_t)NM_*D_*Q_;              // [512, 8, 64, 64]
  float* mu   = invD + (size_t)NM_*8*64*64;         // [256, 3, 512]
  float* w    = mu + (size_t)B_*3*D_;               // [256, 2, 512]
  float* cnt  = w + (size_t)B_*2*S_;                // [256, 2]
  size_t need = ((size_t)(cnt + B_*2) - (size_t)d_ws);
  if (ws_size < need) return;  // workspace too small: fail cleanly

  k_stats<<<dim3(B_), dim3(TPB), 0, stream>>>(X, lab, sl, mu, w, cnt);
  k_gram<<<dim3(36, B_), dim3(TPB), 0, stream>>>(X, w, mu, cnt, sl, A);
  for (int j=0; j<NT; j++){
    k_chol_diag<<<dim3(NM_), dim3(TPB), 0, stream>>>(A, invD, j);
    int nb = NT-1-j;
    if (nb > 0) k_panel<<<dim3(nb, NM_), dim3(TPB), 0, stream>>>(A, invD, j);
    int np = nb*(nb+1)/2;
    if (np > 0) k_trail<<<dim3(np, NM_), dim3(TPB), 0, stream>>>(A, j);
  }
  k_rform<<<dim3(32, NM_), dim3(TPB), 0, stream>>>(Qs, mu, Z);
  for (int j=0; j<NT; j++)
    k_solve<<<dim3(Q_/NB, NM_), dim3(TPB), 0, stream>>>(Z, A, invD, j);
  k_final<<<dim3(B_), dim3(TPB), 0, stream>>>(Z, ql, lps, out);
}

// Round 2
// 3044.046 us; speedup vs baseline: 1.2303x; 1.2303x over previous
//
#include <hip/hip_runtime.h>
#include <hip/hip_bf16.h>

#define TPB 256
constexpr int B_ = 256, S_ = 512, D_ = 512, Q_ = 256, NM_ = 512;
constexpr int NB = 64, NT = 8;

typedef _Float16 f16x8 __attribute__((ext_vector_type(8)));
typedef float f32x4 __attribute__((ext_vector_type(4)));

// ---------------- stats: counts, means, pos bitmask ----------------
__global__ __launch_bounds__(TPB) void k_stats(const float* __restrict__ X,
                                               const int* __restrict__ labels,
                                               const int* __restrict__ slen,
                                               float* __restrict__ mu,
                                               float* __restrict__ cnt,
                                               unsigned int* __restrict__ wpbits)
{
  int b = blockIdx.x, t = threadIdx.x;
  __shared__ int lab[S_];
  __shared__ float red[TPB];
  int L = slen[b];
  for (int s = t; s < S_; s += TPB) {
    int lb = labels[b*S_ + s];
    lab[s] = (s < L) ? lb : -1;
  }
  __syncthreads();
  if (t < 16) {
    unsigned int wword = 0;
    for (int i2 = 0; i2 < 32; i2++) if (lab[t*32 + i2] == 1) wword |= (1u << i2);
    wpbits[b*16 + t] = wword;
  }
  int cpi=0, cni=0;
  for (int s=t; s<S_; s+=TPB){ cpi += (lab[s]==1); cni += (lab[s]==0); }
  red[t] = (float)cpi; __syncthreads();
  for (int o=TPB/2;o>0;o>>=1){ if(t<o) red[t]+=red[t+o]; __syncthreads(); }
  float cp = red[0]; __syncthreads();
  red[t] = (float)cni; __syncthreads();
  for (int o=TPB/2;o>0;o>>=1){ if(t<o) red[t]+=red[t+o]; __syncthreads(); }
  float cn = red[0];
  if (t==0){ cnt[b*2+0]=cn; cnt[b*2+1]=cp; }
  float sp0=0,sp1=0,sn0=0,sn1=0;
  const float* Xb = X + (size_t)b*S_*D_;
  for (int s=0;s<S_;s++){
    int e = lab[s];
    if (e < 0) continue;
    float x0 = Xb[(size_t)s*D_ + t];
    float x1 = Xb[(size_t)s*D_ + t + 256];
    if (e==1){ sp0+=x0; sp1+=x1; } else { sn0+=x0; sn1+=x1; }
  }
  float stv = (float)L;
  float* mb = mu + (size_t)b*3*D_;
  mb[0*D_ + t] = sn0/cn;        mb[0*D_ + t+256] = sn1/cn;
  mb[1*D_ + t] = sp0/cp;        mb[1*D_ + t+256] = sp1/cp;
  mb[2*D_ + t] = (sn0+sp0)/stv; mb[2*D_ + t+256] = (sn1+sp1)/stv;
}

// ---------------- prep: transpose X -> f16 hi/lo [B][D][S], valid-masked ----------------
__global__ __launch_bounds__(TPB) void k_prep(const float* __restrict__ X,
                                              const int* __restrict__ slen,
                                              unsigned short* __restrict__ Xvh,
                                              unsigned short* __restrict__ Xvl)
{
  int b = blockIdx.y, z = blockIdx.x;
  int d0 = (z>>3)*64, s0 = (z&7)*64;
  int t = threadIdx.x;
  __shared__ float Tl[64][65];
  const float* src = X + ((size_t)b*S_ + s0)*D_ + d0;
  { int r = t>>2, seg = (t&3)*16;
    const float4* s4 = (const float4*)(src + (size_t)r*D_ + seg);
    #pragma unroll
    for (int i=0;i<4;i++){ float4 v = s4[i];
      Tl[seg+i*4+0][r]=v.x; Tl[seg+i*4+1][r]=v.y; Tl[seg+i*4+2][r]=v.z; Tl[seg+i*4+3][r]=v.w; } }
  __syncthreads();
  int L = slen[b];
  int dr = t>>2, sc = (t&3)*16;
  union U16 { unsigned short u[8]; uint4 v; };
  U16 H[2], Lo[2];
  #pragma unroll
  for (int g=0; g<2; g++)
    #pragma unroll
    for (int i=0;i<8;i++){
      int si = sc + g*8 + i;
      float x = (s0+si < L) ? Tl[dr][si] : 0.f;
      _Float16 hh = (_Float16)x;
      float lo = x - (float)hh;
      H[g].u[i]  = __builtin_bit_cast(unsigned short, hh);
      Lo[g].u[i] = __builtin_bit_cast(unsigned short, (_Float16)lo);
    }
  size_t o = ((size_t)b*D_ + d0+dr)*S_ + s0 + sc;
  *(uint4*)(Xvh+o)   = H[0].v;  *(uint4*)(Xvh+o+8) = H[1].v;
  *(uint4*)(Xvl+o)   = Lo[0].v; *(uint4*)(Xvl+o+8) = Lo[1].v;
}

// ---------------- MFMA Gram -> A matrices (upper triangle tiles) ----------------
__global__ __launch_bounds__(TPB,2) void k_gram(const unsigned short* __restrict__ Xvh,
                                                const unsigned short* __restrict__ Xvl,
                                                const unsigned int* __restrict__ wpbits,
                                                const float* __restrict__ mu,
                                                const float* __restrict__ cnt,
                                                const int* __restrict__ slen,
                                                float* __restrict__ A)
{
  __shared__ unsigned short sAvh[128][32], sAvl[128][32], sAph[128][32], sApl[128][32],
                            sBvh[128][32], sBvl[128][32];
  int id = blockIdx.x;
  int g = id>>3;
  int b = (g/10)*8 + (id&7);      // XCD co-location: all 10 tiles of b on one XCD
  int z = g%10;
  int ti=0; while (z >= 4-ti){ z -= 4-ti; ti++; } int tj = ti + z;
  int i0 = ti*128, j0 = tj*128;
  int t = threadIdx.x, lane = t&63, w = t>>6;
  int wr = w>>1, wc = w&1, l15 = lane&15;

  f32x4 acc_t[4][4], acc_p[4][4];
  f32x4 z4 = {0.f,0.f,0.f,0.f};
  #pragma unroll
  for (int mf=0;mf<4;mf++)
    #pragma unroll
    for (int nf=0;nf<4;nf++){ acc_t[mf][nf]=z4; acc_p[mf][nf]=z4; }

  const size_t baseA = ((size_t)b*D_ + i0)*S_;
  const size_t baseB = ((size_t)b*D_ + j0)*S_;
  int phx = (lane>>4) ^ ((l15>>1)&3);

  for (int ks=0; ks<16; ks++){
    int s0 = ks*32;
    unsigned int wpw = wpbits[b*16 + ks];
    __syncthreads();
    #pragma unroll
    for (int h=0; h<2; h++){
      int ci = t + h*256;
      int row = ci>>2, cpos = ci&3;
      int ph = cpos ^ ((row>>1)&3);
      size_t ga = baseA + (size_t)row*S_ + s0 + cpos*8;
      size_t gb = baseB + (size_t)row*S_ + s0 + cpos*8;
      uint4 vh = *(const uint4*)(Xvh+ga);
      uint4 vl = *(const uint4*)(Xvl+ga);
      uint4 bh = *(const uint4*)(Xvh+gb);
      uint4 bl = *(const uint4*)(Xvl+gb);
      unsigned int m8 = (wpw >> (cpos*8)) & 0xFFu;
      uint4 mk;
      mk.x = ((m8&1u)?0xFFFFu:0u)  | ((m8&2u)?0xFFFF0000u:0u);
      mk.y = ((m8&4u)?0xFFFFu:0u)  | ((m8&8u)?0xFFFF0000u:0u);
      mk.z = ((m8&16u)?0xFFFFu:0u) | ((m8&32u)?0xFFFF0000u:0u);
      mk.w = ((m8&64u)?0xFFFFu:0u) | ((m8&128u)?0xFFFF0000u:0u);
      uint4 p4, q4;
      p4.x = vh.x&mk.x; p4.y = vh.y&mk.y; p4.z = vh.z&mk.z; p4.w = vh.w&mk.w;
      q4.x = vl.x&mk.x; q4.y = vl.y&mk.y; q4.z = vl.z&mk.z; q4.w = vl.w&mk.w;
      *(uint4*)&sAvh[row][ph*8] = vh;
      *(uint4*)&sAvl[row][ph*8] = vl;
      *(uint4*)&sAph[row][ph*8] = p4;
      *(uint4*)&sApl[row][ph*8] = q4;
      *(uint4*)&sBvh[row][ph*8] = bh;
      *(uint4*)&sBvl[row][ph*8] = bl;
    }
    __syncthreads();
    f16x8 Avh[4], Avl[4], Aph[4], Apl[4];
    #pragma unroll
    for (int mf=0;mf<4;mf++){
      int r = wr*64 + mf*16 + l15;
      Avh[mf] = __builtin_bit_cast(f16x8, *(const uint4*)&sAvh[r][phx*8]);
      Avl[mf] = __builtin_bit_cast(f16x8, *(const uint4*)&sAvl[r][phx*8]);
      Aph[mf] = __builtin_bit_cast(f16x8, *(const uint4*)&sAph[r][phx*8]);
      Apl[mf] = __builtin_bit_cast(f16x8, *(const uint4*)&sApl[r][phx*8]);
    }
    #pragma unroll
    for (int nf=0;nf<4;nf++){
      int r = wc*64 + nf*16 + l15;
      f16x8 Bh = __builtin_bit_cast(f16x8, *(const uint4*)&sBvh[r][phx*8]);
      f16x8 Bl = __builtin_bit_cast(f16x8, *(const uint4*)&sBvl[r][phx*8]);
      #pragma unroll
      for (int mf=0;mf<4;mf++){
        acc_t[mf][nf] = __builtin_amdgcn_mfma_f32_16x16x32_f16(Avh[mf], Bh, acc_t[mf][nf],0,0,0);
        acc_t[mf][nf] = __builtin_amdgcn_mfma_f32_16x16x32_f16(Avh[mf], Bl, acc_t[mf][nf],0,0,0);
        acc_t[mf][nf] = __builtin_amdgcn_mfma_f32_16x16x32_f16(Avl[mf], Bh, acc_t[mf][nf],0,0,0);
        acc_p[mf][nf] = __builtin_amdgcn_mfma_f32_16x16x32_f16(Aph[mf], Bh, acc_p[mf][nf],0,0,0);
        acc_p[mf][nf] = __builtin_amdgcn_mfma_f32_16x16x32_f16(Aph[mf], Bl, acc_p[mf][nf],0,0,0);
        acc_p[mf][nf] = __builtin_amdgcn_mfma_f32_16x16x32_f16(Apl[mf], Bh, acc_p[mf][nf],0,0,0);
      }
    }
  }
  // epilogue: fused rank-1 corrections + ridge, upper tile only
  float cn = cnt[b*2+0], cp = cnt[b*2+1];
  float stv = (float)slen[b];
  float kn = 0.1f/(cn-1.f), kp = 0.1f/(cp-1.f), kt = 0.9f/(stv-1.f);
  float rn = 0.1f*cn/(cn-1.f), rp = 0.1f*cp/(cp-1.f), rt = 0.9f*stv/(stv-1.f);
  const float* mb = mu + (size_t)b*3*D_;
  float* A0 = A + (size_t)(b*2+0)*D_*D_;
  float* A1 = A + (size_t)(b*2+1)*D_*D_;
  int rbase = i0 + wr*64 + (lane>>4)*4;
  int cbase = j0 + wc*64 + l15;
  #pragma unroll
  for (int mf=0;mf<4;mf++){
    #pragma unroll
    for (int i=0;i<4;i++){
      int r = rbase + mf*16 + i;
      float mnr = mb[r], mpr = mb[D_+r], mtr = mb[2*D_+r];
      #pragma unroll
      for (int nf=0;nf<4;nf++){
        int c = cbase + nf*16;
        float mnc = mb[c], mpc = mb[D_+c], mtc = mb[2*D_+c];
        float gp = acc_p[mf][nf][i];
        float gt = acc_t[mf][nf][i];
        float gn = gt - gp;
        float diag = (r==c)?0.1f:0.f;
        A0[(size_t)r*D_ + c] = kn*gn + kt*gt - rn*mnr*mnc - rt*mtr*mtc + diag;
        A1[(size_t)r*D_ + c] = kp*gp + kt*gt - rp*mpr*mpc - rt*mtr*mtc + diag;
      }
    }
  }
}

// ---------------- mirror upper 64-blocks to lower (coalesced LDS transpose) ----------------
__global__ __launch_bounds__(TPB) void k_mirror(float* __restrict__ A)
{
  int m = blockIdx.y, z = blockIdx.x;
  int p = 0; while (z >= 7-p){ z -= 7-p; p++; } int q = p+1+z;   // p<q
  __shared__ float Tl[64][65];
  int t = threadIdx.x;
  float* Am = A + (size_t)m*D_*D_;
  const float* src = Am + (size_t)(p*64)*D_ + q*64;
  { int r = t>>2, seg = (t&3)*16;
    const float4* s4 = (const float4*)(src + (size_t)r*D_ + seg);
    #pragma unroll
    for (int i=0;i<4;i++){ float4 v = s4[i];
      Tl[seg+i*4+0][r]=v.x; Tl[seg+i*4+1][r]=v.y; Tl[seg+i*4+2][r]=v.z; Tl[seg+i*4+3][r]=v.w; } }
  __syncthreads();
  int r2 = t>>2, seg = (t&3)*16;
  float* dst = Am + (size_t)(q*64 + r2)*D_ + p*64 + seg;
  #pragma unroll
  for (int i=0;i<16;i+=4){
    float4 o = make_float4(Tl[r2][seg+i], Tl[r2][seg+i+1], Tl[r2][seg+i+2], Tl[r2][seg+i+3]);
    *(float4*)(dst + i) = o;
  }
}

// stage transposed: dst[col][row] = src[row][col], 64x64 tile
__device__ __forceinline__ void stage_T(const float* __restrict__ src, size_t ld,
                                        float (*dst)[68], int t)
{
  int r = t >> 2, seg = (t & 3) * 16;
  const float4* s4 = (const float4*)(src + (size_t)r*ld + seg);
  #pragma unroll
  for (int i=0;i<4;i++){
    float4 v = s4[i];
    dst[seg + i*4 + 0][r] = v.x;
    dst[seg + i*4 + 1][r] = v.y;
    dst[seg + i*4 + 2][r] = v.z;
    dst[seg + i*4 + 3][r] = v.w;
  }
}

// ---------------- fused blocked Cholesky (one block per matrix) ----------------
__global__ __launch_bounds__(TPB) void k_chol(float* __restrict__ A, float* __restrict__ invD)
{
  int m = blockIdx.x, t = threadIdx.x;
  int tr = t&15, tc = t>>4;
  __shared__ float Ld[64][65], Iv[64][65], Ta[64][68], Tb[64][68];
  float* Am = A + (size_t)m*D_*D_;
  for (int j=0;j<NT;j++){
    float* Ab = Am + (size_t)(j*NB)*D_ + j*NB;
    __syncthreads();
    for (int l=t; l<4096; l+=TPB){ int r=l>>6, c=l&63; Ld[r][c] = Ab[(size_t)r*D_ + c]; Iv[r][c] = 0.f; }
    __syncthreads();
    for (int k=0;k<64;k++){
      if (t==0) Ld[k][k] = sqrtf(Ld[k][k]);
      __syncthreads();
      if (t>k && t<64) Ld[t][k] /= Ld[k][k];
      __syncthreads();
      for (int l=t; l<4096; l+=TPB){
        int r=l>>6, c=l&63;
        if (r>k && c>k) Ld[r][c] = fmaf(-Ld[r][k], Ld[c][k], Ld[r][c]);
      }
      __syncthreads();
    }
    if (t < 64){
      int c = t;
      Iv[c][c] = 1.f/Ld[c][c];
      for (int r=c+1;r<64;r++){
        float s = 0.f;
        for (int k2=c;k2<r;k2++) s += Ld[r][k2]*Iv[k2][c];
        Iv[r][c] = -s/Ld[r][r];
      }
    }
    __syncthreads();
    float* Ib = invD + ((size_t)m*8 + j)*4096;
    for (int l=t; l<4096; l+=TPB){ Ib[l] = Iv[l>>6][l&63]; }
    // IvT -> Tb for fast panel reads
    for (int l=t; l<4096; l+=TPB){ int k=l>>6, c=l&63; Tb[k][c] = Iv[c][k]; }
    __syncthreads();
    // panel: L_ij = A_ij * invD^T
    for (int ib=j+1; ib<NT; ib++){
      float* Ablk = Am + (size_t)(ib*NB)*D_ + j*NB;
      stage_T(Ablk, D_, Ta, t);
      __syncthreads();
      float acc[4][4] = {};
      for (int kk=0; kk<64; kk++){
        float4 av = *((const float4*)&Ta[kk][tr*4]);
        float4 bv = *((const float4*)&Tb[kk][tc*4]);
        float a[4]={av.x,av.y,av.z,av.w}, bb2[4]={bv.x,bv.y,bv.z,bv.w};
        #pragma unroll
        for (int u=0;u<4;u++)
          #pragma unroll
          for (int v=0;v<4;v++) acc[u][v] = fmaf(a[u], bb2[v], acc[u][v]);
      }
      #pragma unroll
      for (int u=0;u<4;u++){
        float4 o = make_float4(acc[u][0],acc[u][1],acc[u][2],acc[u][3]);
        *((float4*)(Ablk + (size_t)(tr*4+u)*D_ + tc*4)) = o;
      }
      __syncthreads();
    }
    // trailing: A_ik -= L_ij * L_kj^T   (k<=i, both > j)
    for (int ib=j+1; ib<NT; ib++){
      __syncthreads();
      stage_T(Am + (size_t)(ib*NB)*D_ + j*NB, D_, Ta, t);
      for (int kb=j+1; kb<=ib; kb++){
        __syncthreads();
        stage_T(Am + (size_t)(kb*NB)*D_ + j*NB, D_, Tb, t);
        __syncthreads();
        float acc[4][4] = {};
        for (int kk=0;kk<64;kk++){
          float4 av = *((const float4*)&Ta[kk][tr*4]);
          float4 bv = *((const float4*)&Tb[kk][tc*4]);
          float a[4]={av.x,av.y,av.z,av.w}, bb2[4]={bv.x,bv.y,bv.z,bv.w};
          #pragma unroll
          for (int u=0;u<4;u++)
            #pragma unroll
            for (int v=0;v<4;v++) acc[u][v] = fmaf(a[u], bb2[v], acc[u][v]);
        }
        float* Cb = Am + (size_t)(ib*NB)*D_ + kb*NB;
        #pragma unroll
        for (int u=0;u<4;u++){
          float4* pC = (float4*)(Cb + (size_t)(tr*4+u)*D_ + tc*4);
          float4 o = *pC;
          o.x -= acc[u][0]; o.y -= acc[u][1]; o.z -= acc[u][2]; o.w -= acc[u][3];
          *pC = o;
        }
      }
    }
  }
}

// ---------------- fused rform + forward solve + maha + logits ----------------
__global__ __launch_bounds__(TPB) void k_solvefin(const float* __restrict__ Qs,
                                                  const float* __restrict__ mu,
                                                  const float* __restrict__ A,
                                                  const float* __restrict__ invD,
                                                  float* __restrict__ Z,
                                                  const int* __restrict__ qlen,
                                                  const float* __restrict__ lps,
                                                  float* __restrict__ out)
{
  int m = blockIdx.y, q0 = blockIdx.x*NB;
  int b = m>>1, cls = m&1;
  int t = threadIdx.x, tr = t&15, tc = t>>4;
  __shared__ float Ta[64][68], Tb[64][68];
  const float* Am = A + (size_t)m*D_*D_;
  float* Zm = Z + (size_t)m*D_*Q_;
  const float* muv = mu + ((size_t)b*3 + cls)*D_;
  float cs[4] = {0.f,0.f,0.f,0.f};
  for (int j=0;j<NT;j++){
    // init acc = mu - Qs^T  (folds k_rform)
    stage_T(Qs + ((size_t)b*Q_ + q0)*D_ + j*NB, D_, Ta, t);
    __syncthreads();
    float acc[4][4];
    #pragma unroll
    for (int u=0;u<4;u++){
      float mrow = muv[j*NB + tr*4 + u];
      #pragma unroll
      for (int v=0;v<4;v++) acc[u][v] = mrow - Ta[tr*4+u][tc*4+v];
    }
    __syncthreads();
    for (int k=0;k<j;k++){
      stage_T(Am + (size_t)(j*NB)*D_ + k*NB, D_, Ta, t);      // L_jk^T
      { int r = t >> 2, seg = (t & 3)*16;
        const float4* s4 = (const float4*)(Zm + (size_t)(k*NB + r)*Q_ + q0 + seg);
        #pragma unroll
        for (int i=0;i<4;i++) *((float4*)&Tb[r][seg + i*4]) = s4[i];
      }
      __syncthreads();
      for (int kk=0;kk<64;kk++){
        float4 av = *((const float4*)&Ta[kk][tr*4]);
        float4 bv = *((const float4*)&Tb[kk][tc*4]);
        float a[4]={av.x,av.y,av.z,av.w}, bb2[4]={bv.x,bv.y,bv.z,bv.w};
        #pragma unroll
        for (int u=0;u<4;u++)
          #pragma unroll
          for (int v=0;v<4;v++) acc[u][v] = fmaf(-a[u], bb2[v], acc[u][v]);
      }
      __syncthreads();
    }
    // Z_j = invD * S
    #pragma unroll
    for (int u=0;u<4;u++)
      #pragma unroll
      for (int v=0;v<4;v++) Tb[tr*4+u][tc*4+v] = acc[u][v];
    stage_T(invD + ((size_t)m*8 + j)*4096, 64, Ta, t);
    __syncthreads();
    float o4[4][4] = {};
    for (int kk=0;kk<64;kk++){
      float4 av = *((const float4*)&Ta[kk][tr*4]);
      float4 bv = *((const float4*)&Tb[kk][tc*4]);
      float a[4]={av.x,av.y,av.z,av.w}, bb2[4]={bv.x,bv.y,bv.z,bv.w};
      #pragma unroll
      for (int u=0;u<4;u++)
        #pragma unroll
        for (int v=0;v<4;v++) o4[u][v] = fmaf(a[u], bb2[v], o4[u][v]);
    }
    if (j < NT-1){
      #pragma unroll
      for (int u=0;u<4;u++){
        float4 o = make_float4(o4[u][0], o4[u][1], o4[u][2], o4[u][3]);
        *((float4*)(Zm + (size_t)(j*NB + tr*4+u)*Q_ + q0 + tc*4)) = o;
      }
    }
    #pragma unroll
    for (int u=0;u<4;u++)
      #pragma unroll
      for (int v=0;v<4;v++) cs[v] = fmaf(o4[u][v], o4[u][v], cs[v]);
    __syncthreads();
  }
  // reduce maha over the 16 row-thread groups, write logits
  float* red = &Ta[0][0];
  #pragma unroll
  for (int v=0;v<4;v++) red[(tc*4+v)*16 + tr] = cs[v];
  __syncthreads();
  if (t < 64){
    float s = 0.f;
    #pragma unroll
    for (int i=0;i<16;i++) s += red[t*16 + i];
    int q = q0 + t;
    float valid = (q < qlen[b]) ? 1.f : 0.f;
    float s2 = expf(2.f*lps[0]);
    out[((size_t)b*Q_ + q)*2 + cls] = -s2*s*valid;
  }
}

extern "C" void kernel_launch(void* const* d_in, const int* in_sizes, int n_in,
                              void* d_out, int out_size, void* d_ws, size_t ws_size,
                              hipStream_t stream) {
  (void)in_sizes; (void)n_in; (void)out_size;
  const float* X   = (const float*)d_in[0];
  const int*   lab = (const int*)d_in[1];
  const float* Qs  = (const float*)d_in[2];
  const int*   sl  = (const int*)d_in[3];
  const int*   ql  = (const int*)d_in[4];
  const float* lps = (const float*)d_in[5];
  float* out = (float*)d_out;

  float* A  = (float*)d_ws;                          // [512,512,512] f32
  float* Z  = A + (size_t)NM_*D_*D_;                 // [512,512,256] f32 (overlaps Xvh/Xvl)
  unsigned short* Xvh = (unsigned short*)Z;          // [256,512,512] f16 bits
  unsigned short* Xvl = Xvh + (size_t)B_*D_*S_;      // [256,512,512] f16 bits
  float* invD = Z + (size_t)NM_*D_*Q_;               // [512,8,64,64] f32
  float* mu   = invD + (size_t)NM_*8*64*64;          // [256,3,512]
  float* cnt  = mu + (size_t)B_*3*D_;                // [256,2]
  unsigned int* wpbits = (unsigned int*)(cnt + B_*2);// [256,16]
  size_t need = (size_t)((char*)(wpbits + B_*16) - (char*)d_ws);
  if (ws_size < need) return;

  k_stats<<<dim3(B_), dim3(TPB), 0, stream>>>(X, lab, sl, mu, cnt, wpbits);
  k_prep<<<dim3(64, B_), dim3(TPB), 0, stream>>>(X, sl, Xvh, Xvl);
  k_gram<<<dim3(2560), dim3(TPB), 0, stream>>>(Xvh, Xvl, wpbits, mu, cnt, sl, A);
  k_mirror<<<dim3(28, NM_), dim3(TPB), 0, stream>>>(A);
  k_chol<<<dim3(NM_), dim3(TPB), 0, stream>>>(A, invD);
  k_solvefin<<<dim3(Q_/NB, NM_), dim3(TPB), 0, stream>>>(Qs, mu, A, invD, Z, ql, lps, out);
}

// Round 3
// 2742.851 us; speedup vs baseline: 1.3654x; 1.1098x over previous
//
#include <hip/hip_runtime.h>
#include <hip/hip_bf16.h>

#define TPB 256
constexpr int B_ = 256, S_ = 512, D_ = 512, Q_ = 256, NM_ = 512;
constexpr int NB = 64, NT = 8;

typedef _Float16 f16x8 __attribute__((ext_vector_type(8)));
typedef float f32x4 __attribute__((ext_vector_type(4)));

// XCD-co-locating decode: x=bid&7 -> XCD; per XCD: tiles fastest, then cls, then group.
// m = matrix index [0,512), consistent XCD (= (m>>1)&7) across ALL launches.
__device__ __forceinline__ void decode_mt(int bid, int W, int& m, int& t){
  int x = bid & 7, r = bid >> 3;
  t = r % W; int u = r / W;
  m = (((u >> 1)*8 + x) << 1) | (u & 1);
}

// direct row-major 64x64 stage: dst[r][c] = src[r][c]
__device__ __forceinline__ void stage_D(const float* __restrict__ src, size_t ld,
                                        float (*dst)[68], int t)
{
  int r = t >> 2, seg = (t & 3) * 16;
  const float4* s4 = (const float4*)(src + (size_t)r*ld + seg);
  #pragma unroll
  for (int i=0;i<4;i++) *((float4*)&dst[r][seg + i*4]) = s4[i];
}

// transposed stage: dst[col][row] = src[row][col]
__device__ __forceinline__ void stage_T(const float* __restrict__ src, size_t ld,
                                        float (*dst)[68], int t)
{
  int r = t >> 2, seg = (t & 3) * 16;
  const float4* s4 = (const float4*)(src + (size_t)r*ld + seg);
  #pragma unroll
  for (int i=0;i<4;i++){
    float4 v = s4[i];
    dst[seg + i*4 + 0][r] = v.x;
    dst[seg + i*4 + 1][r] = v.y;
    dst[seg + i*4 + 2][r] = v.z;
    dst[seg + i*4 + 3][r] = v.w;
  }
}

// ---------------- stats: counts, means, pos bitmask ----------------
__global__ __launch_bounds__(TPB) void k_stats(const float* __restrict__ X,
                                               const int* __restrict__ labels,
                                               const int* __restrict__ slen,
                                               float* __restrict__ mu,
                                               float* __restrict__ cnt,
                                               unsigned int* __restrict__ wpbits)
{
  int b = blockIdx.x, t = threadIdx.x;
  __shared__ int lab[S_];
  __shared__ float red[TPB];
  int L = slen[b];
  for (int s = t; s < S_; s += TPB) {
    int lb = labels[b*S_ + s];
    lab[s] = (s < L) ? lb : -1;
  }
  __syncthreads();
  if (t < 16) {
    unsigned int wword = 0;
    for (int i2 = 0; i2 < 32; i2++) if (lab[t*32 + i2] == 1) wword |= (1u << i2);
    wpbits[b*16 + t] = wword;
  }
  int cpi=0, cni=0;
  for (int s=t; s<S_; s+=TPB){ cpi += (lab[s]==1); cni += (lab[s]==0); }
  red[t] = (float)cpi; __syncthreads();
  for (int o=TPB/2;o>0;o>>=1){ if(t<o) red[t]+=red[t+o]; __syncthreads(); }
  float cp = red[0]; __syncthreads();
  red[t] = (float)cni; __syncthreads();
  for (int o=TPB/2;o>0;o>>=1){ if(t<o) red[t]+=red[t+o]; __syncthreads(); }
  float cn = red[0];
  if (t==0){ cnt[b*2+0]=cn; cnt[b*2+1]=cp; }
  float sp0=0,sp1=0,sn0=0,sn1=0;
  const float* Xb = X + (size_t)b*S_*D_;
  for (int s=0;s<S_;s++){
    int e = lab[s];
    if (e < 0) continue;
    float x0 = Xb[(size_t)s*D_ + t];
    float x1 = Xb[(size_t)s*D_ + t + 256];
    if (e==1){ sp0+=x0; sp1+=x1; } else { sn0+=x0; sn1+=x1; }
  }
  float stv = (float)L;
  float* mb = mu + (size_t)b*3*D_;
  mb[0*D_ + t] = sn0/cn;        mb[0*D_ + t+256] = sn1/cn;
  mb[1*D_ + t] = sp0/cp;        mb[1*D_ + t+256] = sp1/cp;
  mb[2*D_ + t] = (sn0+sp0)/stv; mb[2*D_ + t+256] = (sn1+sp1)/stv;
}

// ---------------- prep: transpose X -> f16 hi/lo [B][D][S], valid-masked ----------------
__global__ __launch_bounds__(TPB) void k_prep(const float* __restrict__ X,
                                              const int* __restrict__ slen,
                                              unsigned short* __restrict__ Xvh,
                                              unsigned short* __restrict__ Xvl)
{
  int b = blockIdx.y, z = blockIdx.x;
  int d0 = (z>>3)*64, s0 = (z&7)*64;
  int t = threadIdx.x;
  __shared__ float Tl[64][65];
  const float* src = X + ((size_t)b*S_ + s0)*D_ + d0;
  { int r = t>>2, seg = (t&3)*16;
    const float4* s4 = (const float4*)(src + (size_t)r*D_ + seg);
    #pragma unroll
    for (int i=0;i<4;i++){ float4 v = s4[i];
      Tl[seg+i*4+0][r]=v.x; Tl[seg+i*4+1][r]=v.y; Tl[seg+i*4+2][r]=v.z; Tl[seg+i*4+3][r]=v.w; } }
  __syncthreads();
  int L = slen[b];
  int dr = t>>2, sc = (t&3)*16;
  union U16 { unsigned short u[8]; uint4 v; };
  U16 H[2], Lo[2];
  #pragma unroll
  for (int g=0; g<2; g++)
    #pragma unroll
    for (int i=0;i<8;i++){
      int si = sc + g*8 + i;
      float x = (s0+si < L) ? Tl[dr][si] : 0.f;
      _Float16 hh = (_Float16)x;
      float lo = x - (float)hh;
      H[g].u[i]  = __builtin_bit_cast(unsigned short, hh);
      Lo[g].u[i] = __builtin_bit_cast(unsigned short, (_Float16)lo);
    }
  size_t o = ((size_t)b*D_ + d0+dr)*S_ + s0 + sc;
  *(uint4*)(Xvh+o)   = H[0].v;  *(uint4*)(Xvh+o+8) = H[1].v;
  *(uint4*)(Xvl+o)   = Lo[0].v; *(uint4*)(Xvl+o+8) = Lo[1].v;
}

// ---------------- MFMA Gram -> A matrices (upper 128-tiles incl. diagonal) ----------------
__global__ __launch_bounds__(TPB,2) void k_gram(const unsigned short* __restrict__ Xvh,
                                                const unsigned short* __restrict__ Xvl,
                                                const unsigned int* __restrict__ wpbits,
                                                const float* __restrict__ mu,
                                                const float* __restrict__ cnt,
                                                const int* __restrict__ slen,
                                                float* __restrict__ A)
{
  __shared__ unsigned short sAvh[128][32], sAvl[128][32], sAph[128][32], sApl[128][32],
                            sBvh[128][32], sBvl[128][32];
  int id = blockIdx.x;
  int g = id>>3;
  int b = (g/10)*8 + (id&7);      // XCD co-location: all 10 tiles of b on one XCD
  int z = g%10;
  int ti=0; while (z >= 4-ti){ z -= 4-ti; ti++; } int tj = ti + z;
  int i0 = ti*128, j0 = tj*128;
  int t = threadIdx.x, lane = t&63, w = t>>6;
  int wr = w>>1, wc = w&1, l15 = lane&15;

  f32x4 acc_t[4][4], acc_p[4][4];
  f32x4 z4 = {0.f,0.f,0.f,0.f};
  #pragma unroll
  for (int mf=0;mf<4;mf++)
    #pragma unroll
    for (int nf=0;nf<4;nf++){ acc_t[mf][nf]=z4; acc_p[mf][nf]=z4; }

  const size_t baseA = ((size_t)b*D_ + i0)*S_;
  const size_t baseB = ((size_t)b*D_ + j0)*S_;
  int phx = (lane>>4) ^ ((l15>>1)&3);

  for (int ks=0; ks<16; ks++){
    int s0 = ks*32;
    unsigned int wpw = wpbits[b*16 + ks];
    __syncthreads();
    #pragma unroll
    for (int h=0; h<2; h++){
      int ci = t + h*256;
      int row = ci>>2, cpos = ci&3;
      int ph = cpos ^ ((row>>1)&3);
      size_t ga = baseA + (size_t)row*S_ + s0 + cpos*8;
      size_t gb = baseB + (size_t)row*S_ + s0 + cpos*8;
      uint4 vh = *(const uint4*)(Xvh+ga);
      uint4 vl = *(const uint4*)(Xvl+ga);
      uint4 bh = *(const uint4*)(Xvh+gb);
      uint4 bl = *(const uint4*)(Xvl+gb);
      unsigned int m8 = (wpw >> (cpos*8)) & 0xFFu;
      uint4 mk;
      mk.x = ((m8&1u)?0xFFFFu:0u)  | ((m8&2u)?0xFFFF0000u:0u);
      mk.y = ((m8&4u)?0xFFFFu:0u)  | ((m8&8u)?0xFFFF0000u:0u);
      mk.z = ((m8&16u)?0xFFFFu:0u) | ((m8&32u)?0xFFFF0000u:0u);
      mk.w = ((m8&64u)?0xFFFFu:0u) | ((m8&128u)?0xFFFF0000u:0u);
      uint4 p4, q4;
      p4.x = vh.x&mk.x; p4.y = vh.y&mk.y; p4.z = vh.z&mk.z; p4.w = vh.w&mk.w;
      q4.x = vl.x&mk.x; q4.y = vl.y&mk.y; q4.z = vl.z&mk.z; q4.w = vl.w&mk.w;
      *(uint4*)&sAvh[row][ph*8] = vh;
      *(uint4*)&sAvl[row][ph*8] = vl;
      *(uint4*)&sAph[row][ph*8] = p4;
      *(uint4*)&sApl[row][ph*8] = q4;
      *(uint4*)&sBvh[row][ph*8] = bh;
      *(uint4*)&sBvl[row][ph*8] = bl;
    }
    __syncthreads();
    f16x8 Avh[4], Avl[4], Aph[4], Apl[4];
    #pragma unroll
    for (int mf=0;mf<4;mf++){
      int r = wr*64 + mf*16 + l15;
      Avh[mf] = __builtin_bit_cast(f16x8, *(const uint4*)&sAvh[r][phx*8]);
      Avl[mf] = __builtin_bit_cast(f16x8, *(const uint4*)&sAvl[r][phx*8]);
      Aph[mf] = __builtin_bit_cast(f16x8, *(const uint4*)&sAph[r][phx*8]);
      Apl[mf] = __builtin_bit_cast(f16x8, *(const uint4*)&sApl[r][phx*8]);
    }
    #pragma unroll
    for (int nf=0;nf<4;nf++){
      int r = wc*64 + nf*16 + l15;
      f16x8 Bh = __builtin_bit_cast(f16x8, *(const uint4*)&sBvh[r][phx*8]);
      f16x8 Bl = __builtin_bit_cast(f16x8, *(const uint4*)&sBvl[r][phx*8]);
      #pragma unroll
      for (int mf=0;mf<4;mf++){
        acc_t[mf][nf] = __builtin_amdgcn_mfma_f32_16x16x32_f16(Avh[mf], Bh, acc_t[mf][nf],0,0,0);
        acc_t[mf][nf] = __builtin_amdgcn_mfma_f32_16x16x32_f16(Avh[mf], Bl, acc_t[mf][nf],0,0,0);
        acc_t[mf][nf] = __builtin_amdgcn_mfma_f32_16x16x32_f16(Avl[mf], Bh, acc_t[mf][nf],0,0,0);
        acc_p[mf][nf] = __builtin_amdgcn_mfma_f32_16x16x32_f16(Aph[mf], Bh, acc_p[mf][nf],0,0,0);
        acc_p[mf][nf] = __builtin_amdgcn_mfma_f32_16x16x32_f16(Aph[mf], Bl, acc_p[mf][nf],0,0,0);
        acc_p[mf][nf] = __builtin_amdgcn_mfma_f32_16x16x32_f16(Apl[mf], Bh, acc_p[mf][nf],0,0,0);
      }
    }
  }
  float cn = cnt[b*2+0], cp = cnt[b*2+1];
  float stv = (float)slen[b];
  float kn = 0.1f/(cn-1.f), kp = 0.1f/(cp-1.f), kt = 0.9f/(stv-1.f);
  float rn = 0.1f*cn/(cn-1.f), rp = 0.1f*cp/(cp-1.f), rt = 0.9f*stv/(stv-1.f);
  const float* mb = mu + (size_t)b*3*D_;
  float* A0 = A + (size_t)(b*2+0)*D_*D_;
  float* A1 = A + (size_t)(b*2+1)*D_*D_;
  int rbase = i0 + wr*64 + (lane>>4)*4;
  int cbase = j0 + wc*64 + l15;
  #pragma unroll
  for (int mf=0;mf<4;mf++){
    #pragma unroll
    for (int i=0;i<4;i++){
      int r = rbase + mf*16 + i;
      float mnr = mb[r], mpr = mb[D_+r], mtr = mb[2*D_+r];
      #pragma unroll
      for (int nf=0;nf<4;nf++){
        int c = cbase + nf*16;
        float mnc = mb[c], mpc = mb[D_+c], mtc = mb[2*D_+c];
        float gp = acc_p[mf][nf][i];
        float gt = acc_t[mf][nf][i];
        float gn = gt - gp;
        float diag = (r==c)?0.1f:0.f;
        A0[(size_t)r*D_ + c] = kn*gn + kt*gt - rn*mnr*mnc - rt*mtr*mtc + diag;
        A1[(size_t)r*D_ + c] = kp*gp + kt*gt - rp*mpr*mpc - rt*mtr*mtc + diag;
      }
    }
  }
}

// ---------------- diag block Cholesky + triangular inverse (transposed out) ----------------
__global__ __launch_bounds__(TPB) void k_diag(float* __restrict__ A,
                                              float* __restrict__ invDT, int j)
{
  int m, t0; decode_mt(blockIdx.x, 1, m, t0); (void)t0;
  int t = threadIdx.x;
  __shared__ float Ld[64][65];
  __shared__ float Iv[64][65];
  float* Ab = A + (size_t)m*D_*D_ + (size_t)(j*NB)*D_ + j*NB;   // upper(j,j)
  for (int l=t; l<4096; l+=TPB){ int r=l>>6, c=l&63; Ld[r][c] = Ab[(size_t)r*D_ + c]; Iv[r][c] = 0.f; }
  __syncthreads();
  for (int k=0;k<64;k++){
    if (t==0) Ld[k][k] = sqrtf(Ld[k][k]);
    __syncthreads();
    if (t>k && t<64) Ld[t][k] /= Ld[k][k];
    __syncthreads();
    for (int l=t; l<4096; l+=TPB){
      int r=l>>6, c=l&63;
      if (r>k && c>k) Ld[r][c] = fmaf(-Ld[r][k], Ld[c][k], Ld[r][c]);
    }
    __syncthreads();
  }
  if (t < 64){
    int c = t;
    Iv[c][c] = 1.f/Ld[c][c];
    for (int r=c+1;r<64;r++){
      float s = 0.f;
      for (int k2=c;k2<r;k2++) s += Ld[r][k2]*Iv[k2][c];
      Iv[r][c] = -s/Ld[r][r];
    }
  }
  __syncthreads();
  float* Ib = invDT + ((size_t)m*8 + j)*4096;
  for (int l=t; l<4096; l+=TPB){ Ib[l] = Iv[l&63][l>>6]; }   // invDT[k][r] = invD[r][k]
}

// ---------------- panel: upper(j,ib) <- invD * upper(j,ib)   (= L_ib,j^T) ----------------
__global__ __launch_bounds__(TPB) void k_panel(float* __restrict__ A,
                                               const float* __restrict__ invDT,
                                               int j, int W)
{
  int m, ti; decode_mt(blockIdx.x, W, m, ti);
  int ib = j + 1 + ti;
  int t = threadIdx.x, tr = t&15, tc = t>>4;
  __shared__ float Ta[64][68], Tb[64][68];
  float* U = A + (size_t)m*D_*D_ + (size_t)(j*NB)*D_ + ib*NB;
  stage_D(invDT + ((size_t)m*8 + j)*4096, 64, Ta, t);   // Ta[kk][r] = invD[r][kk]
  stage_D(U, D_, Tb, t);                                 // Tb[kk][c] = U[kk][c]
  __syncthreads();
  float acc[4][4] = {};
  for (int kk=0; kk<64; kk++){
    float4 av = *((const float4*)&Ta[kk][tr*4]);
    float4 bv = *((const float4*)&Tb[kk][tc*4]);
    float a[4]={av.x,av.y,av.z,av.w}, bb2[4]={bv.x,bv.y,bv.z,bv.w};
    #pragma unroll
    for (int u=0;u<4;u++)
      #pragma unroll
      for (int v=0;v<4;v++) acc[u][v] = fmaf(a[u], bb2[v], acc[u][v]);
  }
  #pragma unroll
  for (int u=0;u<4;u++){
    float4 o = make_float4(acc[u][0],acc[u][1],acc[u][2],acc[u][3]);
    *((float4*)(U + (size_t)(tr*4+u)*D_ + tc*4)) = o;
  }
}

// ---------------- trailing: upper(a,b) -= P_a^T P_b,  P_i = upper(j,i) ----------------
__global__ __launch_bounds__(TPB) void k_trail(float* __restrict__ A, int j, int W)
{
  int m, z; decode_mt(blockIdx.x, W, m, z);
  int T = NT - 1 - j;
  int p = 0; while (z >= T - p){ z -= T - p; p++; }
  int a2 = j + 1 + p, b2 = a2 + z;
  int t = threadIdx.x, tr = t&15, tc = t>>4;
  __shared__ float Ta[64][68], Tb[64][68];
  float* Am = A + (size_t)m*D_*D_;
  stage_D(Am + (size_t)(j*NB)*D_ + a2*NB, D_, Ta, t);
  stage_D(Am + (size_t)(j*NB)*D_ + b2*NB, D_, Tb, t);
  __syncthreads();
  float acc[4][4] = {};
  for (int kk=0;kk<64;kk++){
    float4 av = *((const float4*)&Ta[kk][tr*4]);
    float4 bv = *((const float4*)&Tb[kk][tc*4]);
    float a[4]={av.x,av.y,av.z,av.w}, bb2[4]={bv.x,bv.y,bv.z,bv.w};
    #pragma unroll
    for (int u=0;u<4;u++)
      #pragma unroll
      for (int v=0;v<4;v++) acc[u][v] = fmaf(a[u], bb2[v], acc[u][v]);
  }
  float* Cb = Am + (size_t)(a2*NB)*D_ + b2*NB;
  #pragma unroll
  for (int u=0;u<4;u++){
    float4* pC = (float4*)(Cb + (size_t)(tr*4+u)*D_ + tc*4);
    float4 o = *pC;
    o.x -= acc[u][0]; o.y -= acc[u][1]; o.z -= acc[u][2]; o.w -= acc[u][3];
    *pC = o;
  }
}

// ---------------- fused rform + forward solve + maha + logits ----------------
__global__ __launch_bounds__(TPB) void k_solvefin(const float* __restrict__ Qs,
                                                  const float* __restrict__ mu,
                                                  const float* __restrict__ A,
                                                  const float* __restrict__ invDT,
                                                  float* __restrict__ Z,
                                                  const int* __restrict__ qlen,
                                                  const float* __restrict__ lps,
                                                  float* __restrict__ out)
{
  int m, t0; decode_mt(blockIdx.x, 4, m, t0);
  int q0 = t0*NB;
  int b = m>>1, cls = m&1;
  int t = threadIdx.x, tr = t&15, tc = t>>4;
  __shared__ float Ta[64][68], Tb[64][68];
  const float* Am = A + (size_t)m*D_*D_;
  float* Zm = Z + (size_t)m*D_*Q_;
  const float* muv = mu + ((size_t)b*3 + cls)*D_;
  float cs[4] = {0.f,0.f,0.f,0.f};
  for (int j=0;j<NT;j++){
    // init acc = mu - Qs^T  (folds rform)
    stage_T(Qs + ((size_t)b*Q_ + q0)*D_ + j*NB, D_, Ta, t);
    __syncthreads();
    float acc[4][4];
    #pragma unroll
    for (int u=0;u<4;u++){
      float mrow = muv[j*NB + tr*4 + u];
      #pragma unroll
      for (int v=0;v<4;v++) acc[u][v] = mrow - Ta[tr*4+u][tc*4+v];
    }
    __syncthreads();
    for (int k=0;k<j;k++){
      stage_D(Am + (size_t)(k*NB)*D_ + j*NB, D_, Ta, t);   // Ta[kk][r] = L_jk[r][kk]
      { int r = t >> 2, seg = (t & 3)*16;
        const float4* s4 = (const float4*)(Zm + (size_t)(k*NB + r)*Q_ + q0 + seg);
        #pragma unroll
        for (int i=0;i<4;i++) *((float4*)&Tb[r][seg + i*4]) = s4[i];
      }
      __syncthreads();
      for (int kk=0;kk<64;kk++){
        float4 av = *((const float4*)&Ta[kk][tr*4]);
        float4 bv = *((const float4*)&Tb[kk][tc*4]);
        float a[4]={av.x,av.y,av.z,av.w}, bb2[4]={bv.x,bv.y,bv.z,bv.w};
        #pragma unroll
        for (int u=0;u<4;u++)
          #pragma unroll
          for (int v=0;v<4;v++) acc[u][v] = fmaf(-a[u], bb2[v], acc[u][v]);
      }
      __syncthreads();
    }
    // Z_j = invD * S
    #pragma unroll
    for (int u=0;u<4;u++)
      #pragma unroll
      for (int v=0;v<4;v++) Tb[tr*4+u][tc*4+v] = acc[u][v];
    stage_D(invDT + ((size_t)m*8 + j)*4096, 64, Ta, t);    // Ta[kk][r] = invD[r][kk]
    __syncthreads();
    float o4[4][4] = {};
    for (int kk=0;kk<64;kk++){
      float4 av = *((const float4*)&Ta[kk][tr*4]);
      float4 bv = *((const float4*)&Tb[kk][tc*4]);
      float a[4]={av.x,av.y,av.z,av.w}, bb2[4]={bv.x,bv.y,bv.z,bv.w};
      #pragma unroll
      for (int u=0;u<4;u++)
        #pragma unroll
        for (int v=0;v<4;v++) o4[u][v] = fmaf(a[u], bb2[v], o4[u][v]);
    }
    if (j < NT-1){
      #pragma unroll
      for (int u=0;u<4;u++){
        float4 o = make_float4(o4[u][0], o4[u][1], o4[u][2], o4[u][3]);
        *((float4*)(Zm + (size_t)(j*NB + tr*4+u)*Q_ + q0 + tc*4)) = o;
      }
    }
    #pragma unroll
    for (int u=0;u<4;u++)
      #pragma unroll
      for (int v=0;v<4;v++) cs[v] = fmaf(o4[u][v], o4[u][v], cs[v]);
    __syncthreads();
  }
  float* red = &Ta[0][0];
  #pragma unroll
  for (int v=0;v<4;v++) red[(tc*4+v)*16 + tr] = cs[v];
  __syncthreads();
  if (t < 64){
    float s = 0.f;
    #pragma unroll
    for (int i=0;i<16;i++) s += red[t*16 + i];
    int q = q0 + t;
    float valid = (q < qlen[b]) ? 1.f : 0.f;
    float s2 = expf(2.f*lps[0]);
    out[((size_t)b*Q_ + q)*2 + cls] = -s2*s*valid;
  }
}

extern "C" void kernel_launch(void* const* d_in, const int* in_sizes, int n_in,
                              void* d_out, int out_size, void* d_ws, size_t ws_size,
                              hipStream_t stream) {
  (void)in_sizes; (void)n_in; (void)out_size;
  const float* X   = (const float*)d_in[0];
  const int*   lab = (const int*)d_in[1];
  const float* Qs  = (const float*)d_in[2];
  const int*   sl  = (const int*)d_in[3];
  const int*   ql  = (const int*)d_in[4];
  const float* lps = (const float*)d_in[5];
  float* out = (float*)d_out;

  float* A  = (float*)d_ws;                          // [512,512,512] f32
  float* Z  = A + (size_t)NM_*D_*D_;                 // [512,512,256] f32 (overlaps Xvh/Xvl)
  unsigned short* Xvh = (unsigned short*)Z;          // [256,512,512] f16 bits
  unsigned short* Xvl = Xvh + (size_t)B_*D_*S_;      // [256,512,512] f16 bits
  float* invDT = Z + (size_t)NM_*D_*Q_;              // [512,8,64,64] f32 (transposed)
  float* mu   = invDT + (size_t)NM_*8*64*64;         // [256,3,512]
  float* cnt  = mu + (size_t)B_*3*D_;                // [256,2]
  unsigned int* wpbits = (unsigned int*)(cnt + B_*2);// [256,16]
  size_t need = (size_t)((char*)(wpbits + B_*16) - (char*)d_ws);
  if (ws_size < need) return;

  k_stats<<<dim3(B_), dim3(TPB), 0, stream>>>(X, lab, sl, mu, cnt, wpbits);
  k_prep<<<dim3(64, B_), dim3(TPB), 0, stream>>>(X, sl, Xvh, Xvl);
  k_gram<<<dim3(2560), dim3(TPB), 0, stream>>>(Xvh, Xvl, wpbits, mu, cnt, sl, A);
  for (int j=0; j<NT; j++){
    k_diag<<<dim3(NM_), dim3(TPB), 0, stream>>>(A, invDT, j);
    int nb = NT-1-j;
    if (nb > 0) k_panel<<<dim3(NM_*nb), dim3(TPB), 0, stream>>>(A, invDT, j, nb);
    int np = nb*(nb+1)/2;
    if (np > 0) k_trail<<<dim3(NM_*np), dim3(TPB), 0, stream>>>(A, j, np);
  }
  k_solvefin<<<dim3(NM_*4), dim3(TPB), 0, stream>>>(Qs, mu, A, invDT, Z, ql, lps, out);
}